// Round 1
// baseline (442.449 us; speedup 1.0000x reference)
//
#include <hip/hip_runtime.h>
#include <float.h>

#define BB 8
#define HH 256
#define WW 256
#define NPIX 65536          // HH*WW
#define TOT (BB*NPIX)
#define KTOP 80
#define CAP 16384

// ---------------- init per-batch stats ----------------
__global__ void k_init(unsigned* prodMM, unsigned* gaussMM, unsigned* counts) {
    int t = threadIdx.x;
    if (t < BB) {
        prodMM[2*t]   = 0x7f800000u;  // +inf (min slot)
        prodMM[2*t+1] = 0u;           // max slot (all vals >= 0)
        gaussMM[2*t]   = 0x7f800000u;
        gaussMM[2*t+1] = 0u;
        counts[t] = 0u;
    }
}

// ---------------- horizontal 9-tap sums (occ + mass), zero pad ----------------
__global__ void k_row9(const float* __restrict__ vsm,
                       float* __restrict__ so_, float* __restrict__ sm_) {
    int brow = blockIdx.x;          // b*256 + y
    int x = threadIdx.x;
    __shared__ float row[WW];
    float v = vsm[brow*WW + x];
    row[x] = v;
    __syncthreads();
    float so = 0.f, sm = 0.f;
    #pragma unroll
    for (int d = -4; d <= 4; ++d) {
        int xx = x + d;
        if (xx >= 0 && xx < WW) {
            float t = row[xx];
            so += (t > 0.2f) ? 1.f : 0.f;
            sm += t;
        }
    }
    so_[brow*WW + x] = so;
    sm_[brow*WW + x] = sm;
}

// ---------------- vertical 9-tap sums -> prod, per-batch min/max ----------------
__global__ void k_col9(const float* __restrict__ so_, const float* __restrict__ sm_,
                       float* __restrict__ prod, unsigned* prodMM) {
    int brow = blockIdx.x;
    int b = brow >> 8;
    int y = brow & 255;
    int x = threadIdx.x;
    float so = 0.f, sm = 0.f;
    #pragma unroll
    for (int d = -4; d <= 4; ++d) {
        int yy = y + d;
        if (yy >= 0 && yy < HH) {
            int idx = (b*HH + yy)*WW + x;
            so += so_[idx];
            sm += sm_[idx];
        }
    }
    float p = (so * (1.f/81.f)) * (sm * (1.f/81.f));
    prod[brow*WW + x] = p;

    __shared__ float smn[256], smx[256];
    smn[x] = p; smx[x] = p;
    __syncthreads();
    for (int off = 128; off > 0; off >>= 1) {
        if (x < off) {
            smn[x] = fminf(smn[x], smn[x+off]);
            smx[x] = fmaxf(smx[x], smx[x+off]);
        }
        __syncthreads();
    }
    if (x == 0) {
        atomicMin(&prodMM[2*b],   __float_as_uint(smn[0]));
        atomicMax(&prodMM[2*b+1], __float_as_uint(smx[0]));
    }
}

// ---------------- score = vsm * norm01(prod) ----------------
__global__ void k_score(const float* __restrict__ vsm, const float* __restrict__ prod,
                        const unsigned* __restrict__ prodMM, float* __restrict__ score) {
    int brow = blockIdx.x;
    int b = brow >> 8;
    int x = threadIdx.x;
    float mn = __uint_as_float(prodMM[2*b]);
    float mx = __uint_as_float(prodMM[2*b+1]);
    float inv = 1.f / (mx - mn + 1e-6f);
    int idx = brow*WW + x;
    float compact = (prod[idx] - mn) * inv;
    score[idx] = vsm[idx] * compact;
}

// ---------------- horizontal 5-tap max ----------------
__global__ void k_hmax5(const float* __restrict__ score, float* __restrict__ hmax) {
    int brow = blockIdx.x;
    int x = threadIdx.x;
    __shared__ float row[WW];
    row[x] = score[brow*WW + x];
    __syncthreads();
    float m = -FLT_MAX;
    #pragma unroll
    for (int d = -2; d <= 2; ++d) {
        int xx = x + d;
        if (xx >= 0 && xx < WW) m = fmaxf(m, row[xx]);
    }
    hmax[brow*WW + x] = m;
}

// ---------------- vertical 5-tap max + candidate compaction ----------------
__global__ void k_vmax5(const float* __restrict__ hmax, const float* __restrict__ score,
                        unsigned* counts, float* candV, int* candI) {
    int brow = blockIdx.x;
    int b = brow >> 8;
    int y = brow & 255;
    int x = threadIdx.x;
    float m = -FLT_MAX;
    #pragma unroll
    for (int d = -2; d <= 2; ++d) {
        int yy = y + d;
        if (yy >= 0 && yy < HH) m = fmaxf(m, hmax[(b*HH + yy)*WW + x]);
    }
    int p = y*WW + x;
    float s = score[brow*WW + x];
    if (s == m && s > 0.f) {
        unsigned pos = atomicAdd(&counts[b], 1u);
        if (pos < CAP) {
            candV[b*CAP + pos] = s;
            candI[b*CAP + pos] = p;
        }
    }
}

// ---------------- per-batch top-80 + peak params ----------------
__global__ void k_topk(const float* __restrict__ depth, const unsigned* __restrict__ counts,
                       float* candV, const int* __restrict__ candI,
                       float* pvals, float* pxs, float* pys, float* pc) {
    int b = blockIdx.x;
    int tid = threadIdx.x;
    __shared__ float sv[256];
    __shared__ int   si[256];
    __shared__ int   ss[256];
    int cnt = min((int)counts[b], CAP);
    float* cv = candV + b*CAP;
    const int* ci = candI + b*CAP;

    // zero params (padding for <80 peaks)
    for (int k = tid; k < KTOP; k += 256) {
        pvals[b*KTOP + k] = 0.f;
        pxs[b*KTOP + k] = 0.f;
        pys[b*KTOP + k] = 0.f;
        pc[b*KTOP + k] = 0.f;
    }
    __syncthreads();

    for (int it = 0; it < KTOP; ++it) {
        float bv = -1.f; int bi = 0x7fffffff; int bs = -1;
        for (int i = tid; i < cnt; i += 256) {
            float v = cv[i];
            int idx = ci[i];
            if (v > bv || (v == bv && idx < bi)) { bv = v; bi = idx; bs = i; }
        }
        sv[tid] = bv; si[tid] = bi; ss[tid] = bs;
        __syncthreads();
        for (int off = 128; off > 0; off >>= 1) {
            if (tid < off) {
                float v2 = sv[tid+off]; int i2 = si[tid+off];
                if (v2 > sv[tid] || (v2 == sv[tid] && i2 < si[tid])) {
                    sv[tid] = v2; si[tid] = i2; ss[tid] = ss[tid+off];
                }
            }
            __syncthreads();
        }
        float bestv = sv[0];
        if (bestv <= 0.f) break;           // uniform across block
        if (tid == 0) {
            int idx = si[0];
            cv[ss[0]] = -1.f;              // remove from candidate pool
            int yy = idx >> 8, xx = idx & 255;
            float z = depth[b*NPIX + idx];
            z = fmaxf(z, 0.001f);
            float r = fminf(fmaxf(14.f / z, 1.5f), 18.f);
            float s2 = 0.36f * r * r;      // (0.6*r)^2
            pvals[b*KTOP + it] = bestv;
            pxs[b*KTOP + it] = (float)xx;
            pys[b*KTOP + it] = (float)yy;
            pc[b*KTOP + it]  = 1.44269504f / (2.f*s2 + 1e-6f);  // log2(e)/denom
        }
        __syncthreads();                   // cv write visible before next scan
    }
}

// ---------------- dense gaussian splat, max over 80 peaks ----------------
__global__ void k_splat(const float* __restrict__ pvals, const float* __restrict__ pxs,
                        const float* __restrict__ pys, const float* __restrict__ pc,
                        float* __restrict__ gauss, unsigned* gaussMM) {
    int brow = blockIdx.x;
    int b = brow >> 8;
    int y = brow & 255;
    int x = threadIdx.x;
    __shared__ float lv[KTOP], lx[KTOP], ly[KTOP], lc[KTOP];
    if (x < KTOP) {
        lv[x] = pvals[b*KTOP + x];
        lx[x] = pxs[b*KTOP + x];
        ly[x] = pys[b*KTOP + x];
        lc[x] = pc[b*KTOP + x];
    }
    __syncthreads();
    float fx = (float)x, fy = (float)y;
    float g = 0.f;
    #pragma unroll 8
    for (int k = 0; k < KTOP; ++k) {
        float dx = fx - lx[k];
        float dy = fy - ly[k];
        float d2 = dx*dx + dy*dy;
        float m = lv[k] * exp2f(-d2 * lc[k]);
        g = fmaxf(g, m);
    }
    gauss[brow*WW + x] = g;

    __shared__ float smn[256], smx[256];
    smn[x] = g; smx[x] = g;
    __syncthreads();
    for (int off = 128; off > 0; off >>= 1) {
        if (x < off) {
            smn[x] = fminf(smn[x], smn[x+off]);
            smx[x] = fmaxf(smx[x], smx[x+off]);
        }
        __syncthreads();
    }
    if (x == 0) {
        atomicMin(&gaussMM[2*b],   __float_as_uint(smn[0]));
        atomicMax(&gaussMM[2*b+1], __float_as_uint(smx[0]));
    }
}

// ---------------- final norm01 ----------------
__global__ void k_norm(const float* __restrict__ gauss, const unsigned* __restrict__ gaussMM,
                       float* __restrict__ out) {
    int brow = blockIdx.x;
    int b = brow >> 8;
    int x = threadIdx.x;
    float mn = __uint_as_float(gaussMM[2*b]);
    float mx = __uint_as_float(gaussMM[2*b+1]);
    float inv = 1.f / (mx - mn + 1e-6f);
    int idx = brow*WW + x;
    out[idx] = (gauss[idx] - mn) * inv;
}

extern "C" void kernel_launch(void* const* d_in, const int* in_sizes, int n_in,
                              void* d_out, int out_size, void* d_ws, size_t ws_size,
                              hipStream_t stream) {
    const float* vsm   = (const float*)d_in[0];
    const float* depth = (const float*)d_in[1];
    float* out = (float*)d_out;

    // workspace layout
    float* buf0 = (float*)d_ws;          // rowsum occ -> hmax -> (free)
    float* buf1 = buf0 + TOT;            // rowsum mass -> gauss
    float* buf2 = buf1 + TOT;            // prod
    unsigned* prodMM  = (unsigned*)(buf2 + TOT);
    unsigned* gaussMM = prodMM + 2*BB;
    unsigned* counts  = gaussMM + 2*BB;
    float* pvals = (float*)(counts + BB);
    float* pxs = pvals + BB*KTOP;
    float* pys = pxs + BB*KTOP;
    float* pc  = pys + BB*KTOP;
    float* candV = pc + BB*KTOP;
    int*   candI = (int*)(candV + BB*CAP);

    const int NROWS = BB*HH;             // 2048 row-blocks

    k_init <<<1, 64, 0, stream>>>(prodMM, gaussMM, counts);
    k_row9 <<<NROWS, WW, 0, stream>>>(vsm, buf0, buf1);
    k_col9 <<<NROWS, WW, 0, stream>>>(buf0, buf1, buf2, prodMM);
    k_score<<<NROWS, WW, 0, stream>>>(vsm, buf2, prodMM, out);      // score in d_out (temp)
    k_hmax5<<<NROWS, WW, 0, stream>>>(out, buf0);
    k_vmax5<<<NROWS, WW, 0, stream>>>(buf0, out, counts, candV, candI);
    k_topk <<<BB, 256, 0, stream>>>(depth, counts, candV, candI, pvals, pxs, pys, pc);
    k_splat<<<NROWS, WW, 0, stream>>>(pvals, pxs, pys, pc, buf1, gaussMM);
    k_norm <<<NROWS, WW, 0, stream>>>(buf1, gaussMM, out);
}

// Round 2
// 222.977 us; speedup vs baseline: 1.9843x; 1.9843x over previous
//
#include <hip/hip_runtime.h>
#include <float.h>

#define BB 8
#define HH 256
#define WW 256
#define NPIX 65536          // HH*WW
#define TOT (BB*NPIX)
#define KTOP 80
#define CAP 16384
#define SELBINS 4096
#define SELCAP 2048
typedef unsigned long long ull;

// ---------------- horizontal 9-tap sums (occ + mass), zero pad; block 0 inits stats ----------------
__global__ void k_row9(const float* __restrict__ vsm,
                       float* __restrict__ so_, float* __restrict__ sm_,
                       unsigned* prodMM, unsigned* gaussMM, unsigned* counts) {
    int brow = blockIdx.x;          // b*256 + y
    int x = threadIdx.x;
    if (brow == 0 && x < BB) {
        prodMM[2*x]   = 0x7f800000u;  // +inf (min slot)
        prodMM[2*x+1] = 0u;           // max slot (all vals >= 0)
        gaussMM[2*x]   = 0x7f800000u;
        gaussMM[2*x+1] = 0u;
        counts[x] = 0u;
    }
    __shared__ float row[WW];
    float v = vsm[brow*WW + x];
    row[x] = v;
    __syncthreads();
    float so = 0.f, sm = 0.f;
    #pragma unroll
    for (int d = -4; d <= 4; ++d) {
        int xx = x + d;
        if (xx >= 0 && xx < WW) {
            float t = row[xx];
            so += (t > 0.2f) ? 1.f : 0.f;
            sm += t;
        }
    }
    so_[brow*WW + x] = so;
    sm_[brow*WW + x] = sm;
}

// ---------------- vertical 9-tap sums -> prod, per-batch min/max ----------------
__global__ void k_col9(const float* __restrict__ so_, const float* __restrict__ sm_,
                       float* __restrict__ prod, unsigned* prodMM) {
    int brow = blockIdx.x;
    int b = brow >> 8;
    int y = brow & 255;
    int x = threadIdx.x;
    float so = 0.f, sm = 0.f;
    #pragma unroll
    for (int d = -4; d <= 4; ++d) {
        int yy = y + d;
        if (yy >= 0 && yy < HH) {
            int idx = (b*HH + yy)*WW + x;
            so += so_[idx];
            sm += sm_[idx];
        }
    }
    float p = (so * (1.f/81.f)) * (sm * (1.f/81.f));
    prod[brow*WW + x] = p;

    __shared__ float smn[256], smx[256];
    smn[x] = p; smx[x] = p;
    __syncthreads();
    for (int off = 128; off > 0; off >>= 1) {
        if (x < off) {
            smn[x] = fminf(smn[x], smn[x+off]);
            smx[x] = fmaxf(smx[x], smx[x+off]);
        }
        __syncthreads();
    }
    if (x == 0) {
        atomicMin(&prodMM[2*b],   __float_as_uint(smn[0]));
        atomicMax(&prodMM[2*b+1], __float_as_uint(smx[0]));
    }
}

// ---------------- score = vsm * norm01(prod), fused 5-tap horizontal max ----------------
__global__ void k_score_hmax(const float* __restrict__ vsm, const float* __restrict__ prod,
                             const unsigned* __restrict__ prodMM,
                             float* __restrict__ score, float* __restrict__ hmax) {
    int brow = blockIdx.x;
    int b = brow >> 8;
    int x = threadIdx.x;
    float mn = __uint_as_float(prodMM[2*b]);
    float mx = __uint_as_float(prodMM[2*b+1]);
    float inv = 1.f / (mx - mn + 1e-6f);
    int idx = brow*WW + x;
    float s = vsm[idx] * ((prod[idx] - mn) * inv);
    __shared__ float row[WW];
    row[x] = s;
    score[idx] = s;
    __syncthreads();
    float m = s;
    #pragma unroll
    for (int d = -2; d <= 2; ++d) {
        int xx = x + d;
        if (d != 0 && xx >= 0 && xx < WW) m = fmaxf(m, row[xx]);
    }
    hmax[idx] = m;
}

// ---------------- vertical 5-tap max + candidate compaction ----------------
__global__ void k_vmax5(const float* __restrict__ hmax, const float* __restrict__ score,
                        unsigned* counts, float* candV, int* candI) {
    int brow = blockIdx.x;
    int b = brow >> 8;
    int y = brow & 255;
    int x = threadIdx.x;
    float m = -FLT_MAX;
    #pragma unroll
    for (int d = -2; d <= 2; ++d) {
        int yy = y + d;
        if (yy >= 0 && yy < HH) m = fmaxf(m, hmax[(b*HH + yy)*WW + x]);
    }
    int p = y*WW + x;
    float s = score[brow*WW + x];
    if (s == m && s > 0.f) {
        unsigned pos = atomicAdd(&counts[b], 1u);
        if (pos < CAP) {
            candV[b*CAP + pos] = s;
            candI[b*CAP + pos] = p;
        }
    }
}

// ---------------- per-batch exact top-80: histogram select + bitonic sort ----------------
__global__ void __launch_bounds__(1024)
k_topk(const float* __restrict__ depth, const unsigned* __restrict__ counts,
       const float* __restrict__ candV, const int* __restrict__ candI,
       float* __restrict__ pvals, float* __restrict__ pxs,
       float* __restrict__ pys, float* __restrict__ pc) {
    int b = blockIdx.x;
    int tid = threadIdx.x;
    __shared__ unsigned hist[SELBINS];
    __shared__ unsigned sc[1024];
    __shared__ ull keyAll[SELCAP];
    __shared__ int sBin;
    __shared__ unsigned sN;

    int cnt = min((int)counts[b], CAP);
    const float* cv = candV + b*CAP;
    const int* ci = candI + b*CAP;

    #pragma unroll
    for (int i = 0; i < SELBINS/1024; ++i) hist[tid + i*1024] = 0;
    if (tid == 0) { sBin = 0; sN = 0; }
    __syncthreads();

    // pass 1: histogram of float-bit bins (positive floats: bit order == value order)
    for (int i = tid; i < cnt; i += 1024)
        atomicAdd(&hist[__float_as_uint(cv[i]) >> 19], 1u);
    __syncthreads();

    // suffix scan: find largest bin B with suffix(B) >= KTOP
    int j0 = tid * 4;
    unsigned h0 = hist[j0], h1 = hist[j0+1], h2 = hist[j0+2], h3 = hist[j0+3];
    unsigned part = h0 + h1 + h2 + h3;
    sc[tid] = part;
    __syncthreads();
    for (int off = 1; off < 1024; off <<= 1) {
        unsigned v = (tid + off < 1024) ? sc[tid + off] : 0u;
        __syncthreads();
        sc[tid] += v;
        __syncthreads();
    }
    unsigned excl = sc[tid] - part;        // sum over threads > tid
    unsigned suf3 = excl + h3;
    unsigned suf2 = suf3 + h2;
    unsigned suf1 = suf2 + h1;
    unsigned suf0 = suf1 + h0;
    // exactly one bin satisfies when total >= KTOP; else sBin stays 0 (take all)
    if (suf0 >= KTOP && suf0 - h0 < KTOP) sBin = j0;
    if (suf1 >= KTOP && suf1 - h1 < KTOP) sBin = j0 + 1;
    if (suf2 >= KTOP && suf2 - h2 < KTOP) sBin = j0 + 2;
    if (suf3 >= KTOP && suf3 - h3 < KTOP) sBin = j0 + 3;
    __syncthreads();

    // pass 2: collect keys in bins >= B  (key = valbits:~idx -> desc val, asc idx)
    int B = sBin;
    for (int i = tid; i < cnt; i += 1024) {
        unsigned bits = __float_as_uint(cv[i]);
        if ((int)(bits >> 19) >= B) {
            unsigned p = atomicAdd(&sN, 1u);
            if (p < SELCAP) keyAll[p] = ((ull)bits << 32) | (ull)(0xFFFFFFFFu - (unsigned)ci[i]);
        }
    }
    __syncthreads();
    unsigned n = min(sN, (unsigned)SELCAP);
    unsigned P = 128; while (P < n) P <<= 1;
    for (unsigned i = n + tid; i < P; i += 1024) keyAll[i] = 0ull;
    __syncthreads();

    // bitonic sort ascending; winners are the top (last) K entries
    for (unsigned k = 2; k <= P; k <<= 1) {
        for (unsigned j = k >> 1; j > 0; j >>= 1) {
            for (unsigned i = tid; i < P; i += 1024) {
                unsigned ixj = i ^ j;
                if (ixj > i) {
                    ull a = keyAll[i], c = keyAll[ixj];
                    bool up = ((i & k) == 0);
                    if (up ? (a > c) : (a < c)) { keyAll[i] = c; keyAll[ixj] = a; }
                }
            }
            __syncthreads();
        }
    }

    // emit peak params
    if (tid < KTOP) {
        unsigned K = min((unsigned)KTOP, n);
        float val = 0.f, fx = 0.f, fy = 0.f, c = 0.f;
        if ((unsigned)tid < K) {
            ull key = keyAll[P - 1 - tid];
            unsigned bits = (unsigned)(key >> 32);
            int idx = (int)(0xFFFFFFFFu - (unsigned)(key & 0xFFFFFFFFu));
            val = __uint_as_float(bits);
            fx = (float)(idx & 255);
            fy = (float)(idx >> 8);
            float z = fmaxf(depth[b*NPIX + idx], 0.001f);
            float r = fminf(fmaxf(14.f / z, 1.5f), 18.f);
            float s2 = 0.36f * r * r;                     // (0.6*r)^2
            c = 1.44269504f / (2.f * s2 + 1e-6f);         // log2(e)/denom
        }
        pvals[b*KTOP + tid] = val;
        pxs[b*KTOP + tid] = fx;
        pys[b*KTOP + tid] = fy;
        pc[b*KTOP + tid]  = c;
    }
}

// ---------------- dense gaussian splat, max over 80 peaks ----------------
__global__ void k_splat(const float* __restrict__ pvals, const float* __restrict__ pxs,
                        const float* __restrict__ pys, const float* __restrict__ pc,
                        float* __restrict__ gauss, unsigned* gaussMM) {
    int brow = blockIdx.x;
    int b = brow >> 8;
    int y = brow & 255;
    int x = threadIdx.x;
    __shared__ float lv[KTOP], lx[KTOP], ly[KTOP], lc[KTOP];
    if (x < KTOP) {
        lv[x] = pvals[b*KTOP + x];
        lx[x] = pxs[b*KTOP + x];
        ly[x] = pys[b*KTOP + x];
        lc[x] = pc[b*KTOP + x];
    }
    __syncthreads();
    float fx = (float)x, fy = (float)y;
    float g = 0.f;
    #pragma unroll 8
    for (int k = 0; k < KTOP; ++k) {
        float dx = fx - lx[k];
        float dy = fy - ly[k];
        float d2 = dx*dx + dy*dy;
        float m = lv[k] * exp2f(-d2 * lc[k]);
        g = fmaxf(g, m);
    }
    gauss[brow*WW + x] = g;

    __shared__ float smn[256], smx[256];
    smn[x] = g; smx[x] = g;
    __syncthreads();
    for (int off = 128; off > 0; off >>= 1) {
        if (x < off) {
            smn[x] = fminf(smn[x], smn[x+off]);
            smx[x] = fmaxf(smx[x], smx[x+off]);
        }
        __syncthreads();
    }
    if (x == 0) {
        atomicMin(&gaussMM[2*b],   __float_as_uint(smn[0]));
        atomicMax(&gaussMM[2*b+1], __float_as_uint(smx[0]));
    }
}

// ---------------- final norm01 ----------------
__global__ void k_norm(const float* __restrict__ gauss, const unsigned* __restrict__ gaussMM,
                       float* __restrict__ out) {
    int brow = blockIdx.x;
    int b = brow >> 8;
    int x = threadIdx.x;
    float mn = __uint_as_float(gaussMM[2*b]);
    float mx = __uint_as_float(gaussMM[2*b+1]);
    float inv = 1.f / (mx - mn + 1e-6f);
    int idx = brow*WW + x;
    out[idx] = (gauss[idx] - mn) * inv;
}

extern "C" void kernel_launch(void* const* d_in, const int* in_sizes, int n_in,
                              void* d_out, int out_size, void* d_ws, size_t ws_size,
                              hipStream_t stream) {
    const float* vsm   = (const float*)d_in[0];
    const float* depth = (const float*)d_in[1];
    float* out = (float*)d_out;

    // workspace layout
    float* buf0 = (float*)d_ws;          // rowsum occ -> hmax
    float* buf1 = buf0 + TOT;            // rowsum mass -> gauss
    float* buf2 = buf1 + TOT;            // prod
    unsigned* prodMM  = (unsigned*)(buf2 + TOT);
    unsigned* gaussMM = prodMM + 2*BB;
    unsigned* counts  = gaussMM + 2*BB;
    float* pvals = (float*)(counts + BB);
    float* pxs = pvals + BB*KTOP;
    float* pys = pxs + BB*KTOP;
    float* pc  = pys + BB*KTOP;
    float* candV = pc + BB*KTOP;
    int*   candI = (int*)(candV + BB*CAP);

    const int NROWS = BB*HH;             // 2048 row-blocks

    k_row9      <<<NROWS, WW, 0, stream>>>(vsm, buf0, buf1, prodMM, gaussMM, counts);
    k_col9      <<<NROWS, WW, 0, stream>>>(buf0, buf1, buf2, prodMM);
    k_score_hmax<<<NROWS, WW, 0, stream>>>(vsm, buf2, prodMM, out, buf0);   // score in d_out (temp)
    k_vmax5     <<<NROWS, WW, 0, stream>>>(buf0, out, counts, candV, candI);
    k_topk      <<<BB, 1024, 0, stream>>>(depth, counts, candV, candI, pvals, pxs, pys, pc);
    k_splat     <<<NROWS, WW, 0, stream>>>(pvals, pxs, pys, pc, buf1, gaussMM);
    k_norm      <<<NROWS, WW, 0, stream>>>(buf1, gaussMM, out);
}

// Round 3
// 162.973 us; speedup vs baseline: 2.7149x; 1.3682x over previous
//
#include <hip/hip_runtime.h>
#include <float.h>

#define BB 8
#define HH 256
#define WW 256
#define NPIX 65536          // HH*WW
#define TOT (BB*NPIX)
#define KTOP 80
#define CAP 16384
#define SELBINS 4096
#define SELCAP 2048
typedef unsigned long long ull;

// ---------------- horizontal 9-tap sums (occ + mass), zero pad; block 0 inits stats ----------------
__global__ void k_row9(const float* __restrict__ vsm,
                       float* __restrict__ so_, float* __restrict__ sm_,
                       unsigned* prodMM, unsigned* gaussMM, unsigned* counts) {
    int brow = blockIdx.x;          // b*256 + y
    int x = threadIdx.x;
    if (brow == 0 && x < BB) {
        prodMM[2*x]   = 0x7f800000u;  // +inf (min slot)
        prodMM[2*x+1] = 0u;           // max slot (all vals >= 0)
        gaussMM[2*x]   = 0x7f800000u;
        gaussMM[2*x+1] = 0u;
        counts[x] = 0u;
    }
    __shared__ float row[WW];
    float v = vsm[brow*WW + x];
    row[x] = v;
    __syncthreads();
    float so = 0.f, sm = 0.f;
    #pragma unroll
    for (int d = -4; d <= 4; ++d) {
        int xx = x + d;
        if (xx >= 0 && xx < WW) {
            float t = row[xx];
            so += (t > 0.2f) ? 1.f : 0.f;
            sm += t;
        }
    }
    so_[brow*WW + x] = so;
    sm_[brow*WW + x] = sm;
}

// ---------------- vertical 9-tap sums -> prod, per-batch min/max ----------------
__global__ void k_col9(const float* __restrict__ so_, const float* __restrict__ sm_,
                       float* __restrict__ prod, unsigned* prodMM) {
    int brow = blockIdx.x;
    int b = brow >> 8;
    int y = brow & 255;
    int x = threadIdx.x;
    float so = 0.f, sm = 0.f;
    #pragma unroll
    for (int d = -4; d <= 4; ++d) {
        int yy = y + d;
        if (yy >= 0 && yy < HH) {
            int idx = (b*HH + yy)*WW + x;
            so += so_[idx];
            sm += sm_[idx];
        }
    }
    float p = (so * (1.f/81.f)) * (sm * (1.f/81.f));
    prod[brow*WW + x] = p;

    __shared__ float smn[256], smx[256];
    smn[x] = p; smx[x] = p;
    __syncthreads();
    for (int off = 128; off > 0; off >>= 1) {
        if (x < off) {
            smn[x] = fminf(smn[x], smn[x+off]);
            smx[x] = fmaxf(smx[x], smx[x+off]);
        }
        __syncthreads();
    }
    if (x == 0) {
        atomicMin(&prodMM[2*b],   __float_as_uint(smn[0]));
        atomicMax(&prodMM[2*b+1], __float_as_uint(smx[0]));
    }
}

// ---------------- score = vsm * norm01(prod), fused 5-tap horizontal max ----------------
__global__ void k_score_hmax(const float* __restrict__ vsm, const float* __restrict__ prod,
                             const unsigned* __restrict__ prodMM,
                             float* __restrict__ score, float* __restrict__ hmax) {
    int brow = blockIdx.x;
    int b = brow >> 8;
    int x = threadIdx.x;
    float mn = __uint_as_float(prodMM[2*b]);
    float mx = __uint_as_float(prodMM[2*b+1]);
    float inv = 1.f / (mx - mn + 1e-6f);
    int idx = brow*WW + x;
    float s = vsm[idx] * ((prod[idx] - mn) * inv);
    __shared__ float row[WW];
    row[x] = s;
    score[idx] = s;
    __syncthreads();
    float m = s;
    #pragma unroll
    for (int d = -2; d <= 2; ++d) {
        int xx = x + d;
        if (d != 0 && xx >= 0 && xx < WW) m = fmaxf(m, row[xx]);
    }
    hmax[idx] = m;
}

// ---------------- vertical 5-tap max + block-aggregated candidate compaction ----------------
__global__ void k_vmax5(const float* __restrict__ hmax, const float* __restrict__ score,
                        unsigned* counts, float* candV, int* candI) {
    int brow = blockIdx.x;
    int b = brow >> 8;
    int y = brow & 255;
    int x = threadIdx.x;
    float m = -FLT_MAX;
    #pragma unroll
    for (int d = -2; d <= 2; ++d) {
        int yy = y + d;
        if (yy >= 0 && yy < HH) m = fmaxf(m, hmax[(b*HH + yy)*WW + x]);
    }
    int p = y*WW + x;
    float s = score[brow*WW + x];
    bool isPeak = (s == m && s > 0.f);

    // hierarchical compaction: wave ballot -> block total -> ONE atomic per block
    ull mask = __ballot(isPeak);
    int lane = x & 63;
    int wid = x >> 6;
    __shared__ unsigned wbase[4];
    if (lane == 0) wbase[wid] = (unsigned)__popcll(mask);
    __syncthreads();
    if (x == 0) {
        unsigned tot = wbase[0] + wbase[1] + wbase[2] + wbase[3];
        unsigned base = tot ? atomicAdd(&counts[b], tot) : 0u;
        unsigned acc = base;
        #pragma unroll
        for (int w = 0; w < 4; ++w) { unsigned c = wbase[w]; wbase[w] = acc; acc += c; }
    }
    __syncthreads();
    if (isPeak) {
        unsigned pos = wbase[wid] + (unsigned)__popcll(mask & ((1ull << lane) - 1ull));
        if (pos < CAP) {
            candV[b*CAP + pos] = s;
            candI[b*CAP + pos] = p;
        }
    }
}

// ---------------- per-batch exact top-80: histogram select + bitonic sort ----------------
__global__ void __launch_bounds__(1024)
k_topk(const float* __restrict__ depth, const unsigned* __restrict__ counts,
       const float* __restrict__ candV, const int* __restrict__ candI,
       float* __restrict__ pvals, float* __restrict__ pxs,
       float* __restrict__ pys, float* __restrict__ pc) {
    int b = blockIdx.x;
    int tid = threadIdx.x;
    __shared__ unsigned hist[SELBINS];
    __shared__ unsigned sc[1024];
    __shared__ ull keyAll[SELCAP];
    __shared__ int sBin;
    __shared__ unsigned sN;

    int cnt = min((int)counts[b], CAP);
    const float* cv = candV + b*CAP;
    const int* ci = candI + b*CAP;

    #pragma unroll
    for (int i = 0; i < SELBINS/1024; ++i) hist[tid + i*1024] = 0;
    if (tid == 0) { sBin = 0; sN = 0; }
    __syncthreads();

    // pass 1: histogram of float-bit bins (positive floats: bit order == value order)
    for (int i = tid; i < cnt; i += 1024)
        atomicAdd(&hist[__float_as_uint(cv[i]) >> 19], 1u);
    __syncthreads();

    // suffix scan: find largest bin B with suffix(B) >= KTOP
    int j0 = tid * 4;
    unsigned h0 = hist[j0], h1 = hist[j0+1], h2 = hist[j0+2], h3 = hist[j0+3];
    unsigned part = h0 + h1 + h2 + h3;
    sc[tid] = part;
    __syncthreads();
    for (int off = 1; off < 1024; off <<= 1) {
        unsigned v = (tid + off < 1024) ? sc[tid + off] : 0u;
        __syncthreads();
        sc[tid] += v;
        __syncthreads();
    }
    unsigned excl = sc[tid] - part;        // sum over threads > tid
    unsigned suf3 = excl + h3;
    unsigned suf2 = suf3 + h2;
    unsigned suf1 = suf2 + h1;
    unsigned suf0 = suf1 + h0;
    if (suf0 >= KTOP && suf0 - h0 < KTOP) sBin = j0;
    if (suf1 >= KTOP && suf1 - h1 < KTOP) sBin = j0 + 1;
    if (suf2 >= KTOP && suf2 - h2 < KTOP) sBin = j0 + 2;
    if (suf3 >= KTOP && suf3 - h3 < KTOP) sBin = j0 + 3;
    __syncthreads();

    // pass 2: collect keys in bins >= B  (key = valbits:~idx -> desc val, asc idx)
    int B = sBin;
    for (int i = tid; i < cnt; i += 1024) {
        unsigned bits = __float_as_uint(cv[i]);
        if ((int)(bits >> 19) >= B) {
            unsigned p = atomicAdd(&sN, 1u);
            if (p < SELCAP) keyAll[p] = ((ull)bits << 32) | (ull)(0xFFFFFFFFu - (unsigned)ci[i]);
        }
    }
    __syncthreads();
    unsigned n = min(sN, (unsigned)SELCAP);
    unsigned P = 128; while (P < n) P <<= 1;
    for (unsigned i = n + tid; i < P; i += 1024) keyAll[i] = 0ull;
    __syncthreads();

    // bitonic sort ascending; winners are the top (last) K entries
    for (unsigned k = 2; k <= P; k <<= 1) {
        for (unsigned j = k >> 1; j > 0; j >>= 1) {
            for (unsigned i = tid; i < P; i += 1024) {
                unsigned ixj = i ^ j;
                if (ixj > i) {
                    ull a = keyAll[i], c = keyAll[ixj];
                    bool up = ((i & k) == 0);
                    if (up ? (a > c) : (a < c)) { keyAll[i] = c; keyAll[ixj] = a; }
                }
            }
            __syncthreads();
        }
    }

    // emit peak params
    if (tid < KTOP) {
        unsigned K = min((unsigned)KTOP, n);
        float val = 0.f, fx = 0.f, fy = 0.f, c = 0.f;
        if ((unsigned)tid < K) {
            ull key = keyAll[P - 1 - tid];
            unsigned bits = (unsigned)(key >> 32);
            int idx = (int)(0xFFFFFFFFu - (unsigned)(key & 0xFFFFFFFFu));
            val = __uint_as_float(bits);
            fx = (float)(idx & 255);
            fy = (float)(idx >> 8);
            float z = fmaxf(depth[b*NPIX + idx], 0.001f);
            float r = fminf(fmaxf(14.f / z, 1.5f), 18.f);
            float s2 = 0.36f * r * r;                     // (0.6*r)^2
            c = 1.44269504f / (2.f * s2 + 1e-6f);         // log2(e)/denom
        }
        pvals[b*KTOP + tid] = val;
        pxs[b*KTOP + tid] = fx;
        pys[b*KTOP + tid] = fy;
        pc[b*KTOP + tid]  = c;
    }
}

// ---------------- dense gaussian splat, max over 80 peaks ----------------
__global__ void k_splat(const float* __restrict__ pvals, const float* __restrict__ pxs,
                        const float* __restrict__ pys, const float* __restrict__ pc,
                        float* __restrict__ gauss, unsigned* gaussMM) {
    int brow = blockIdx.x;
    int b = brow >> 8;
    int y = brow & 255;
    int x = threadIdx.x;
    __shared__ float lv[KTOP], lx[KTOP], ly[KTOP], lc[KTOP];
    if (x < KTOP) {
        lv[x] = pvals[b*KTOP + x];
        lx[x] = pxs[b*KTOP + x];
        ly[x] = pys[b*KTOP + x];
        lc[x] = pc[b*KTOP + x];
    }
    __syncthreads();
    float fx = (float)x, fy = (float)y;
    float g = 0.f;
    #pragma unroll 8
    for (int k = 0; k < KTOP; ++k) {
        float dx = fx - lx[k];
        float dy = fy - ly[k];
        float d2 = dx*dx + dy*dy;
        float m = lv[k] * exp2f(-d2 * lc[k]);
        g = fmaxf(g, m);
    }
    gauss[brow*WW + x] = g;

    __shared__ float smn[256], smx[256];
    smn[x] = g; smx[x] = g;
    __syncthreads();
    for (int off = 128; off > 0; off >>= 1) {
        if (x < off) {
            smn[x] = fminf(smn[x], smn[x+off]);
            smx[x] = fmaxf(smx[x], smx[x+off]);
        }
        __syncthreads();
    }
    if (x == 0) {
        atomicMin(&gaussMM[2*b],   __float_as_uint(smn[0]));
        atomicMax(&gaussMM[2*b+1], __float_as_uint(smx[0]));
    }
}

// ---------------- final norm01 ----------------
__global__ void k_norm(const float* __restrict__ gauss, const unsigned* __restrict__ gaussMM,
                       float* __restrict__ out) {
    int brow = blockIdx.x;
    int b = brow >> 8;
    int x = threadIdx.x;
    float mn = __uint_as_float(gaussMM[2*b]);
    float mx = __uint_as_float(gaussMM[2*b+1]);
    float inv = 1.f / (mx - mn + 1e-6f);
    int idx = brow*WW + x;
    out[idx] = (gauss[idx] - mn) * inv;
}

extern "C" void kernel_launch(void* const* d_in, const int* in_sizes, int n_in,
                              void* d_out, int out_size, void* d_ws, size_t ws_size,
                              hipStream_t stream) {
    const float* vsm   = (const float*)d_in[0];
    const float* depth = (const float*)d_in[1];
    float* out = (float*)d_out;

    // workspace layout
    float* buf0 = (float*)d_ws;          // rowsum occ -> hmax
    float* buf1 = buf0 + TOT;            // rowsum mass -> gauss
    float* buf2 = buf1 + TOT;            // prod
    unsigned* prodMM  = (unsigned*)(buf2 + TOT);
    unsigned* gaussMM = prodMM + 2*BB;
    unsigned* counts  = gaussMM + 2*BB;
    float* pvals = (float*)(counts + BB);
    float* pxs = pvals + BB*KTOP;
    float* pys = pxs + BB*KTOP;
    float* pc  = pys + BB*KTOP;
    float* candV = pc + BB*KTOP;
    int*   candI = (int*)(candV + BB*CAP);

    const int NROWS = BB*HH;             // 2048 row-blocks

    k_row9      <<<NROWS, WW, 0, stream>>>(vsm, buf0, buf1, prodMM, gaussMM, counts);
    k_col9      <<<NROWS, WW, 0, stream>>>(buf0, buf1, buf2, prodMM);
    k_score_hmax<<<NROWS, WW, 0, stream>>>(vsm, buf2, prodMM, out, buf0);   // score in d_out (temp)
    k_vmax5     <<<NROWS, WW, 0, stream>>>(buf0, out, counts, candV, candI);
    k_topk      <<<BB, 1024, 0, stream>>>(depth, counts, candV, candI, pvals, pxs, pys, pc);
    k_splat     <<<NROWS, WW, 0, stream>>>(pvals, pxs, pys, pc, buf1, gaussMM);
    k_norm      <<<NROWS, WW, 0, stream>>>(buf1, gaussMM, out);
}

// Round 4
// 42.448 us; speedup vs baseline: 10.4232x; 3.8393x over previous
//
#include <hip/hip_runtime.h>
#include <float.h>
#include <math.h>

#define BB 8
#define HH 256
#define WW 256
#define NPIX 65536          // HH*WW
#define TOT (BB*NPIX)
#define KTOP 80
#define NTIL 64             // 8x8 tiles of 32x32 per image
#define TCAP 128            // max candidates kept per tile
#define SELBINS 4096
#define SELCAP 2048
typedef unsigned long long ull;

// ============ fused 9x9 avg-pools -> prod, per-block min/max partials ============
__global__ void k_box9(const float* __restrict__ vsm, float* __restrict__ prod,
                       float* __restrict__ pmn, float* __restrict__ pmx) {
    int blk = blockIdx.x;            // b*64 + tile
    int b = blk >> 6;
    int t = blk & 63;
    int ty0 = (t >> 3) << 5;
    int tx0 = (t & 7) << 5;
    int tid = threadIdx.x;           // 256

    __shared__ float val[40][40];
    __shared__ float rs_o[40][32];
    __shared__ float rs_m[40][32];

    // load 40x40 halo tile (zero pad outside image)
    for (int i = tid; i < 1600; i += 256) {
        int ly = i / 40, lx = i - ly * 40;
        int gy = ty0 - 4 + ly, gx = tx0 - 4 + lx;
        float v = 0.f;
        if (gy >= 0 && gy < HH && gx >= 0 && gx < WW)
            v = vsm[(b * HH + gy) * WW + gx];
        val[ly][lx] = v;
    }
    __syncthreads();

    // horizontal 9-tap sums: 40 rows x 32 output cols
    for (int i = tid; i < 1280; i += 256) {
        int ly = i >> 5, lx = i & 31;
        float so = 0.f, sm = 0.f;
        #pragma unroll
        for (int d = 0; d < 9; ++d) {
            float v = val[ly][lx + d];
            so += (v > 0.2f) ? 1.f : 0.f;
            sm += v;
        }
        rs_o[ly][lx] = so;
        rs_m[ly][lx] = sm;
    }
    __syncthreads();

    // vertical 9-tap sums -> prod; 4 rows per thread
    int ox = tid & 31;
    int oy0 = (tid >> 5) << 2;
    float tmn = FLT_MAX, tmx = -FLT_MAX;
    #pragma unroll
    for (int j = 0; j < 4; ++j) {
        int oy = oy0 + j;
        float so = 0.f, sm = 0.f;
        #pragma unroll
        for (int d = 0; d < 9; ++d) {
            so += rs_o[oy + d][ox];
            sm += rs_m[oy + d][ox];
        }
        float p = (so * (1.f / 81.f)) * (sm * (1.f / 81.f));
        prod[(b * HH + ty0 + oy) * WW + tx0 + ox] = p;
        tmn = fminf(tmn, p);
        tmx = fmaxf(tmx, p);
    }

    __shared__ float smn[256], smx[256];
    smn[tid] = tmn; smx[tid] = tmx;
    __syncthreads();
    for (int off = 128; off > 0; off >>= 1) {
        if (tid < off) {
            smn[tid] = fminf(smn[tid], smn[tid + off]);
            smx[tid] = fmaxf(smx[tid], smx[tid + off]);
        }
        __syncthreads();
    }
    if (tid == 0) { pmn[blk] = smn[0]; pmx[blk] = smx[0]; }
}

// ============ score + 5x5 NMS + per-tile candidate compaction (no global atomics) ============
__global__ void k_nms(const float* __restrict__ vsm, const float* __restrict__ prod,
                      const float* __restrict__ pmn, const float* __restrict__ pmx,
                      unsigned* __restrict__ bcnt, float* __restrict__ candV,
                      int* __restrict__ candI) {
    int blk = blockIdx.x;
    int b = blk >> 6;
    int t = blk & 63;
    int ty0 = (t >> 3) << 5;
    int tx0 = (t & 7) << 5;
    int tid = threadIdx.x;

    // reduce per-batch prod min/max from 64 block partials (wave 0)
    __shared__ float sred[2];
    if (tid < 64) {
        float mn = pmn[b * NTIL + tid];
        float mx = pmx[b * NTIL + tid];
        #pragma unroll
        for (int o = 32; o > 0; o >>= 1) {
            mn = fminf(mn, __shfl_xor(mn, o, 64));
            mx = fmaxf(mx, __shfl_xor(mx, o, 64));
        }
        if (tid == 0) { sred[0] = mn; sred[1] = mx; }
    }
    __syncthreads();
    float mnp = sred[0];
    float inv = 1.f / (sred[1] - mnp + 1e-6f);

    __shared__ float sc[36][36];
    __shared__ float hm[36][32];

    // score for 36x36 halo region (-FLT_MAX outside image)
    for (int i = tid; i < 1296; i += 256) {
        int ly = i / 36, lx = i - ly * 36;
        int gy = ty0 - 2 + ly, gx = tx0 - 2 + lx;
        float s = -FLT_MAX;
        if (gy >= 0 && gy < HH && gx >= 0 && gx < WW) {
            int idx = (b * HH + gy) * WW + gx;
            s = vsm[idx] * ((prod[idx] - mnp) * inv);
        }
        sc[ly][lx] = s;
    }
    __syncthreads();

    // horizontal 5-tap max: 36 rows x 32 cols
    for (int i = tid; i < 1152; i += 256) {
        int ly = i >> 5, lx = i & 31;
        float m = sc[ly][lx];
        #pragma unroll
        for (int d = 1; d < 5; ++d) m = fmaxf(m, sc[ly][lx + d]);
        hm[ly][lx] = m;
    }
    __syncthreads();

    // vertical 5-tap max + peak test; compact via LDS counter
    __shared__ unsigned scnt;
    __shared__ float bv[TCAP];
    __shared__ int bi[TCAP];
    if (tid == 0) scnt = 0;
    __syncthreads();

    int ox = tid & 31;
    int oy0 = (tid >> 5) << 2;
    #pragma unroll
    for (int j = 0; j < 4; ++j) {
        int oy = oy0 + j;
        float m = hm[oy][ox];
        #pragma unroll
        for (int d = 1; d < 5; ++d) m = fmaxf(m, hm[oy + d][ox]);
        float s = sc[oy + 2][ox + 2];
        if (s == m && s > 0.f) {
            unsigned p = atomicAdd(&scnt, 1u);
            if (p < TCAP) {
                bv[p] = s;
                bi[p] = (ty0 + oy) * WW + tx0 + ox;
            }
        }
    }
    __syncthreads();
    unsigned cnt = min(scnt, (unsigned)TCAP);
    if (tid == 0) bcnt[blk] = cnt;
    for (unsigned i = tid; i < cnt; i += 256) {
        candV[blk * TCAP + i] = bv[i];
        candI[blk * TCAP + i] = bi[i];
    }
}

// ============ per-batch exact top-80 (histogram select + bitonic), emit packed params ============
__global__ void __launch_bounds__(1024)
k_topk(const float* __restrict__ depth, const unsigned* __restrict__ bcnt,
       const float* __restrict__ candV, const int* __restrict__ candI,
       float4* __restrict__ pk) {
    int b = blockIdx.x;
    int tid = threadIdx.x;
    __shared__ unsigned hist[SELBINS];
    __shared__ unsigned sc[1024];
    __shared__ ull keyAll[SELCAP];
    __shared__ unsigned bcs[NTIL];
    __shared__ int sBin;
    __shared__ unsigned sN;

    const float* cv = candV + b * NTIL * TCAP;
    const int* ci = candI + b * NTIL * TCAP;

    #pragma unroll
    for (int i = 0; i < SELBINS / 1024; ++i) hist[tid + i * 1024] = 0;
    if (tid < NTIL) bcs[tid] = bcnt[b * NTIL + tid];
    if (tid == 0) { sBin = 0; sN = 0; }
    __syncthreads();

    // pass 1: histogram of float-bit bins (positive floats: bit order == value order)
    for (int i = tid; i < NTIL * TCAP; i += 1024) {
        int tile = i >> 7, o = i & (TCAP - 1);
        if ((unsigned)o < bcs[tile])
            atomicAdd(&hist[__float_as_uint(cv[i]) >> 19], 1u);
    }
    __syncthreads();

    // suffix scan: find largest bin B with suffix(B) >= KTOP
    int j0 = tid * 4;
    unsigned h0 = hist[j0], h1 = hist[j0 + 1], h2 = hist[j0 + 2], h3 = hist[j0 + 3];
    unsigned part = h0 + h1 + h2 + h3;
    sc[tid] = part;
    __syncthreads();
    for (int off = 1; off < 1024; off <<= 1) {
        unsigned v = (tid + off < 1024) ? sc[tid + off] : 0u;
        __syncthreads();
        sc[tid] += v;
        __syncthreads();
    }
    unsigned excl = sc[tid] - part;
    unsigned suf3 = excl + h3;
    unsigned suf2 = suf3 + h2;
    unsigned suf1 = suf2 + h1;
    unsigned suf0 = suf1 + h0;
    if (suf0 >= KTOP && suf0 - h0 < KTOP) sBin = j0;
    if (suf1 >= KTOP && suf1 - h1 < KTOP) sBin = j0 + 1;
    if (suf2 >= KTOP && suf2 - h2 < KTOP) sBin = j0 + 2;
    if (suf3 >= KTOP && suf3 - h3 < KTOP) sBin = j0 + 3;
    __syncthreads();

    // pass 2: collect keys in bins >= B (key = valbits:~idx -> desc val, asc idx)
    int B = sBin;
    for (int i = tid; i < NTIL * TCAP; i += 1024) {
        int tile = i >> 7, o = i & (TCAP - 1);
        if ((unsigned)o < bcs[tile]) {
            unsigned bits = __float_as_uint(cv[i]);
            if ((int)(bits >> 19) >= B) {
                unsigned p = atomicAdd(&sN, 1u);
                if (p < SELCAP)
                    keyAll[p] = ((ull)bits << 32) | (ull)(0xFFFFFFFFu - (unsigned)ci[i]);
            }
        }
    }
    __syncthreads();
    unsigned n = min(sN, (unsigned)SELCAP);
    unsigned P = 128; while (P < n) P <<= 1;
    for (unsigned i = n + tid; i < P; i += 1024) keyAll[i] = 0ull;
    __syncthreads();

    for (unsigned k = 2; k <= P; k <<= 1) {
        for (unsigned j = k >> 1; j > 0; j >>= 1) {
            for (unsigned i = tid; i < P; i += 1024) {
                unsigned ixj = i ^ j;
                if (ixj > i) {
                    ull a = keyAll[i], c = keyAll[ixj];
                    bool up = ((i & k) == 0);
                    if (up ? (a > c) : (a < c)) { keyAll[i] = c; keyAll[ixj] = a; }
                }
            }
            __syncthreads();
        }
    }

    // emit packed peak params: {log2(val), x, y, c}
    if (tid < KTOP) {
        unsigned K = min((unsigned)KTOP, n);
        float plog = -INFINITY, fx = 0.f, fy = 0.f, c = 0.f;
        if ((unsigned)tid < K) {
            ull key = keyAll[P - 1 - tid];
            unsigned bits = (unsigned)(key >> 32);
            int idx = (int)(0xFFFFFFFFu - (unsigned)(key & 0xFFFFFFFFu));
            float val = __uint_as_float(bits);
            plog = log2f(val);
            fx = (float)(idx & 255);
            fy = (float)(idx >> 8);
            float z = fmaxf(depth[b * NPIX + idx], 0.001f);
            float r = fminf(fmaxf(14.f / z, 1.5f), 18.f);
            float s2 = 0.36f * r * r;                       // (0.6*r)^2
            c = 1.44269504f / (2.f * s2 + 1e-6f);           // log2(e)/denom
        }
        pk[b * KTOP + tid] = make_float4(plog, fx, fy, c);
    }
}

// ============ log-domain gaussian splat: 4 px/thread, single exp2 per pixel ============
__global__ void k_splat(const float4* __restrict__ pk, float* __restrict__ gauss,
                        float* __restrict__ gmn, float* __restrict__ gmx) {
    int blk = blockIdx.x;            // b*64 + rowgroup
    int b = blk >> 6;
    int y0 = (blk & 63) << 2;
    int x = threadIdx.x;

    __shared__ float4 lp[KTOP];
    if (x < KTOP) lp[x] = pk[b * KTOP + x];
    __syncthreads();

    float fx = (float)x;
    float fy = (float)y0;
    float g0 = -INFINITY, g1 = -INFINITY, g2 = -INFINITY, g3 = -INFINITY;
    #pragma unroll 4
    for (int k = 0; k < KTOP; ++k) {
        float4 q = lp[k];            // {plog, px, py, c}
        float dx = fx - q.y;
        float dx2 = dx * dx;
        float dy = fy - q.z;
        float d2;
        d2 = fmaf(dy, dy, dx2);           g0 = fmaxf(g0, fmaf(-d2, q.w, q.x));
        float dyb = dy + 1.f;
        d2 = fmaf(dyb, dyb, dx2);         g1 = fmaxf(g1, fmaf(-d2, q.w, q.x));
        float dyc = dy + 2.f;
        d2 = fmaf(dyc, dyc, dx2);         g2 = fmaxf(g2, fmaf(-d2, q.w, q.x));
        float dyd = dy + 3.f;
        d2 = fmaf(dyd, dyd, dx2);         g3 = fmaxf(g3, fmaf(-d2, q.w, q.x));
    }
    float v0 = exp2f(g0), v1 = exp2f(g1), v2 = exp2f(g2), v3 = exp2f(g3);
    int base = (b * HH + y0) * WW + x;
    gauss[base]          = v0;
    gauss[base + WW]     = v1;
    gauss[base + 2 * WW] = v2;
    gauss[base + 3 * WW] = v3;

    float tmn = fminf(fminf(v0, v1), fminf(v2, v3));
    float tmx = fmaxf(fmaxf(v0, v1), fmaxf(v2, v3));
    __shared__ float smn[256], smx[256];
    smn[x] = tmn; smx[x] = tmx;
    __syncthreads();
    for (int off = 128; off > 0; off >>= 1) {
        if (x < off) {
            smn[x] = fminf(smn[x], smn[x + off]);
            smx[x] = fmaxf(smx[x], smx[x + off]);
        }
        __syncthreads();
    }
    if (x == 0) { gmn[blk] = smn[0]; gmx[blk] = smx[0]; }
}

// ============ final norm01 (float4 vectorized) ============
__global__ void k_norm(const float* __restrict__ gauss, const float* __restrict__ gmn,
                       const float* __restrict__ gmx, float* __restrict__ out) {
    int blk = blockIdx.x;            // 512
    int b = blk >> 6;
    int tid = threadIdx.x;

    __shared__ float sred[2];
    if (tid < 64) {
        float mn = gmn[b * NTIL + tid];
        float mx = gmx[b * NTIL + tid];
        #pragma unroll
        for (int o = 32; o > 0; o >>= 1) {
            mn = fminf(mn, __shfl_xor(mn, o, 64));
            mx = fmaxf(mx, __shfl_xor(mx, o, 64));
        }
        if (tid == 0) { sred[0] = mn; sred[1] = mx; }
    }
    __syncthreads();
    float mn = sred[0];
    float inv = 1.f / (sred[1] - mn + 1e-6f);

    int i = blk * 256 + tid;         // float4 index
    float4 v = ((const float4*)gauss)[i];
    v.x = (v.x - mn) * inv;
    v.y = (v.y - mn) * inv;
    v.z = (v.z - mn) * inv;
    v.w = (v.w - mn) * inv;
    ((float4*)out)[i] = v;
}

extern "C" void kernel_launch(void* const* d_in, const int* in_sizes, int n_in,
                              void* d_out, int out_size, void* d_ws, size_t ws_size,
                              hipStream_t stream) {
    const float* vsm   = (const float*)d_in[0];
    const float* depth = (const float*)d_in[1];
    float* out = (float*)d_out;

    // workspace layout (pk first for 16B alignment)
    float4* pk = (float4*)d_ws;                        // BB*KTOP
    float* prod = (float*)(pk + BB * KTOP);            // TOT
    float* gauss = prod + TOT;                         // TOT
    float* pmn = gauss + TOT;                          // 512
    float* pmx = pmn + BB * NTIL;
    float* gmn = pmx + BB * NTIL;
    float* gmx = gmn + BB * NTIL;
    unsigned* bcnt = (unsigned*)(gmx + BB * NTIL);     // 512
    float* candV = (float*)(bcnt + BB * NTIL);         // 512*TCAP
    int* candI = (int*)(candV + BB * NTIL * TCAP);     // 512*TCAP

    const int NBLK = BB * NTIL;                        // 512

    k_box9 <<<NBLK, 256, 0, stream>>>(vsm, prod, pmn, pmx);
    k_nms  <<<NBLK, 256, 0, stream>>>(vsm, prod, pmn, pmx, bcnt, candV, candI);
    k_topk <<<BB, 1024, 0, stream>>>(depth, bcnt, candV, candI, pk);
    k_splat<<<NBLK, 256, 0, stream>>>(pk, gauss, gmn, gmx);
    k_norm <<<NBLK, 256, 0, stream>>>(gauss, gmn, gmx, out);
}